// Round 7
// baseline (177.610 us; speedup 1.0000x reference)
//
#include <hip/hip_runtime.h>
#include <cmath>

// Shapes:
//  fused  [16,64,128,128] f32
//  hf1    [16, 9,256,256] f32
//  hf2    [16, 9,128,128] f32
//  conv_w [3,64,3,3] f32, conv_b [3] f32
//  out    [16,3,512,512] f32
//
// Pipeline (2 kernels):
//  K1 conv8<ICP>: ic-split partial conv -> part [8][16][3][128][128] (25 MB)
//     32-lane sub-wave = one full row (float4/lane); shuffle halo; width-32
//     partition boundary == image edge. 2048 blocks -> ~32 waves/CU.
//  K2 iwt_fused<8>: per-thread sum of 8 partials + bias + tanh, then fused
//     double inverse-Haar (2 output rows/thread). The Hr=2h / 2h+1 threads that
//     share one ll sit in the same block -> duplicate part reads are L1 hits.
//
// R6 post-mortem: kernels sum ~85 us vs ~35 us floor; ~85 us harness overhead
// (ws/out poison + in restore) is inside the timed window and untouchable.

#define H1 128
#define W1 128
#define H2 256
#define W2 256
#define H3 512
#define W3 512
#define IN_CH 64
#define NB 16
#define PLANE (H1 * W1)            // 16384
#define LLSZ (NB * 3 * PLANE)      // 786432 floats per chunk

template <int ICP>
__global__ __launch_bounds__(256) void conv8_kernel(
    const float* __restrict__ fused,
    const float* __restrict__ cw,
    float* __restrict__ part)
{
    // block (32,8): lane 0..31 covers a full 128-col row (4 px each), ty = row.
    // grid (64/ICP, 16, 16).
    const int lane  = threadIdx.x;
    const int ty    = threadIdx.y;
    const int chunk = blockIdx.x;
    const int h     = blockIdx.y * 8 + ty;
    const int b     = blockIdx.z;
    const int w0    = lane * 4;

    float4 acc[3];
    #pragma unroll
    for (int oc = 0; oc < 3; ++oc) { acc[oc].x = acc[oc].y = acc[oc].z = acc[oc].w = 0.f; }

    const float* fc = fused + ((size_t)b * IN_CH + chunk * ICP) * PLANE;

    auto ld = [&](float4 R[3], int ic) {
        const float* fp = fc + (size_t)ic * PLANE;
        #pragma unroll
        for (int r = 0; r < 3; ++r) {
            const int hh = h + r - 1;
            if (((unsigned)hh) < (unsigned)H1) {
                R[r] = *(const float4*)(fp + hh * W1 + w0);
            } else { R[r].x = R[r].y = R[r].z = R[r].w = 0.f; }
        }
    };

    auto comp = [&](const float4 R[3], int ic) {
        float v[3][6];
        #pragma unroll
        for (int r = 0; r < 3; ++r) {
            float left  = __shfl_up(R[r].w, 1, 32);    // width=32: row-confined
            float right = __shfl_down(R[r].x, 1, 32);
            if (lane == 0)  left = 0.f;                // w = -1 (image edge)
            if (lane == 31) right = 0.f;               // w = 128 (image edge)
            v[r][0] = left;  v[r][1] = R[r].x; v[r][2] = R[r].y;
            v[r][3] = R[r].z; v[r][4] = R[r].w; v[r][5] = right;
        }
        #pragma unroll
        for (int oc = 0; oc < 3; ++oc) {
            const float* wp = cw + (oc * IN_CH + chunk * ICP + ic) * 9;  // uniform -> s_load
            #pragma unroll
            for (int kh = 0; kh < 3; ++kh) {
                #pragma unroll
                for (int kw = 0; kw < 3; ++kw) {
                    const float wv = wp[kh * 3 + kw];
                    acc[oc].x = fmaf(v[kh][kw + 0], wv, acc[oc].x);
                    acc[oc].y = fmaf(v[kh][kw + 1], wv, acc[oc].y);
                    acc[oc].z = fmaf(v[kh][kw + 2], wv, acc[oc].z);
                    acc[oc].w = fmaf(v[kh][kw + 3], wv, acc[oc].w);
                }
            }
        }
    };

    // 2-deep software pipeline; NO launch_bounds min-waves cap (R3 spill lesson).
    float4 A[3], B[3];
    ld(A, 0);
    for (int ic = 0; ic < ICP; ic += 2) {
        ld(B, ic + 1);
        comp(A, ic);
        if (ic + 2 < ICP) ld(A, ic + 2);
        comp(B, ic + 1);
    }

    #pragma unroll
    for (int oc = 0; oc < 3; ++oc) {
        *(float4*)(part + (size_t)chunk * LLSZ +
                   (((size_t)(b * 3 + oc)) * H1 + h) * W1 + w0) = acc[oc];
    }
}

// One thread per hf1-row position: sums NCH conv partials + bias + tanh inline,
// then produces 2 output rows (8 px). 1.57M threads, 6144 blocks.
template <int NCH>
__global__ __launch_bounds__(256) void iwt_fused_kernel(
    const float* __restrict__ part,  // [NCH][16][3][128][128]
    const float* __restrict__ cb,    // [3]
    const float* __restrict__ hf2,   // [16,9,128,128]
    const float* __restrict__ hf1,   // [16,9,256,256]
    float* __restrict__ out)         // [16,3,512,512]
{
    const int idx = blockIdx.x * 256 + threadIdx.x;   // 1572864
    const int k    = idx & 127;          // coarse col
    const int Hr   = (idx >> 7) & 255;   // level-1 row
    const int rest = idx >> 15;          // 0..47
    const int c = rest % 3;
    const int b = rest / 3;
    const int h = Hr >> 1;               // coarse row
    const int p = Hr & 1;                // level-1 sub-row

    const size_t llidx = (((size_t)(b * 3 + c)) * H1 + h) * W1 + k;
    float s = 0.f;
    #pragma unroll
    for (int kk = 0; kk < NCH; ++kk) s += part[(size_t)kk * LLSZ + llidx];
    const float llv = tanhf(s + cb[c]);

    const float* h2p = hf2 + (((size_t)(b * 9 + 3 * c)) * H1 + h) * W1 + k;
    const float a2 = h2p[0]         * 2.f - 1.f;   // LH
    const float b2 = h2p[PLANE]     * 2.f - 1.f;   // HL
    const float c2 = h2p[2 * PLANE] * 2.f - 1.f;   // HH
    const float sp = p ? 1.f : -1.f;
    const float m0 = 0.5f * (llv + sp * a2 - b2 - sp * c2);   // level-1 col 2k
    const float m1 = 0.5f * (llv + sp * a2 + b2 + sp * c2);   // level-1 col 2k+1

    const float* h1p = hf1 + ((size_t)(b * 9 + 3 * c)) * (H2 * W2) + (size_t)Hr * W2 + 2 * k;
    const float2 A  = *(const float2*)(h1p);
    const float2 Bv = *(const float2*)(h1p + H2 * W2);
    const float2 Cv = *(const float2*)(h1p + 2 * H2 * W2);
    const float a0 = A.x  * 2.f - 1.f, a1 = A.y  * 2.f - 1.f;
    const float b0 = Bv.x * 2.f - 1.f, b1 = Bv.y * 2.f - 1.f;
    const float c0 = Cv.x * 2.f - 1.f, c1 = Cv.y * 2.f - 1.f;

    float* ob = out + (((size_t)(b * 3 + c)) * H3 + 2 * (size_t)Hr) * W3 + 4 * k;
    float4 o;
    // r = 0 (sr = -1)
    o.x = 0.5f * (m0 - a0 - b0 + c0);
    o.y = 0.5f * (m0 - a0 + b0 - c0);
    o.z = 0.5f * (m1 - a1 - b1 + c1);
    o.w = 0.5f * (m1 - a1 + b1 - c1);
    *(float4*)(ob) = o;
    // r = 1 (sr = +1)
    o.x = 0.5f * (m0 + a0 - b0 - c0);
    o.y = 0.5f * (m0 + a0 + b0 + c0);
    o.z = 0.5f * (m1 + a1 - b1 - c1);
    o.w = 0.5f * (m1 + a1 + b1 + c1);
    *(float4*)(ob + W3) = o;
}

extern "C" void kernel_launch(void* const* d_in, const int* in_sizes, int n_in,
                              void* d_out, int out_size, void* d_ws, size_t ws_size,
                              hipStream_t stream) {
    (void)in_sizes; (void)n_in; (void)out_size;
    const float* fused = (const float*)d_in[0];
    const float* hf1   = (const float*)d_in[1];
    const float* hf2   = (const float*)d_in[2];
    const float* cw    = (const float*)d_in[3];
    const float* cb    = (const float*)d_in[4];
    float* out  = (float*)d_out;
    float* part = (float*)d_ws;

    dim3 cblk(32, 8, 1);
    const int iwtBlocks = (NB * 3 * H2 * W1) / 256;              // 6144

    const size_t need8 = (size_t)8 * LLSZ * sizeof(float);       // 25.2 MB
    if (ws_size >= need8) {
        dim3 cgrd(8, 16, NB);                                    // 2048 blocks
        conv8_kernel<8><<<cgrd, cblk, 0, stream>>>(fused, cw, part);
        iwt_fused_kernel<8><<<iwtBlocks, 256, 0, stream>>>(part, cb, hf2, hf1, out);
    } else {
        dim3 cgrd(1, 16, NB);                                    // 256 blocks
        conv8_kernel<64><<<cgrd, cblk, 0, stream>>>(fused, cw, part);
        iwt_fused_kernel<1><<<iwtBlocks, 256, 0, stream>>>(part, cb, hf2, hf1, out);
    }
}